// Round 17
// baseline (2489.268 us; speedup 1.0000x reference)
//
#include <hip/hip_runtime.h>
#include <hip/hip_fp16.h>

#define T_STEPS 2048
#define BATCH 16
#define DIMD 1024
#define NSTATE 1024
#define MROWS (T_STEPS * BATCH)   // 32768
#define NCH (BATCH * NSTATE)      // 16384

typedef _Float16 f16x8 __attribute__((ext_vector_type(8)));
typedef float f32x4 __attribute__((ext_vector_type(4)));

#define GAS(p) ((const __attribute__((address_space(1))) void*)(p))
#define LAS(p) ((__attribute__((address_space(3))) void*)(p))

// ---------------- f32 -> f16 convert, 8 elements/thread ----------------
__global__ void cvt_kernel(const float* __restrict__ src, _Float16* __restrict__ dst, int n8) {
  int i = blockIdx.x * blockDim.x + threadIdx.x;
  if (i >= n8) return;
  const float4* s4 = (const float4*)src;
  float4 a = s4[(size_t)i * 2];
  float4 b = s4[(size_t)i * 2 + 1];
  f16x8 o;
  o[0] = (_Float16)a.x; o[1] = (_Float16)a.y; o[2] = (_Float16)a.z; o[3] = (_Float16)a.w;
  o[4] = (_Float16)b.x; o[5] = (_Float16)b.y; o[6] = (_Float16)b.z; o[7] = (_Float16)b.w;
  *((f16x8*)dst + i) = o;
}

// one launch for all three W matrices (blockIdx.y selects)
__global__ void cvtW_kernel(const float* __restrict__ wk, const float* __restrict__ wv,
                            const float* __restrict__ wq, _Float16* __restrict__ dst) {
  const float* src = blockIdx.y == 0 ? wk : blockIdx.y == 1 ? wv : wq;
  int i = blockIdx.x * blockDim.x + threadIdx.x;   // < 131072
  const float4* s4 = (const float4*)src;
  float4 a = s4[(size_t)i * 2];
  float4 b = s4[(size_t)i * 2 + 1];
  f16x8 o;
  o[0] = (_Float16)a.x; o[1] = (_Float16)a.y; o[2] = (_Float16)a.z; o[3] = (_Float16)a.w;
  o[4] = (_Float16)b.x; o[5] = (_Float16)b.y; o[6] = (_Float16)b.z; o[7] = (_Float16)b.w;
  *((f16x8*)dst + (size_t)blockIdx.y * (NSTATE * DIMD / 8) + i) = o;
}

// ================= GEMM: 256x256 tile, BK=32, 8 waves, 2-phase, 2 blocks/CU ====
// Same (2,4) decomp and phase bodies as the 206-us champion, but BK 64->32 and
// LDS 128KB->64KB so TWO blocks co-reside per CU: when one block sits in its
// vmcnt(0)+barrier drain, the other issues MFMA/ds_read (m97/m114 mechanism).
__global__ __launch_bounds__(512, 4) void gemm_kernel(const _Float16* __restrict__ A,
                                                      const _Float16* __restrict__ Wcat,
                                                      _Float16* __restrict__ KVQt,
                                                      float* __restrict__ rnpart) {
  __shared__ _Float16 lds[32768];   // [buf:2][region:2 (A,B)][8192]  = 64 KiB
  const int tid = threadIdx.x;
  const int lane = tid & 63;
  const int w = tid >> 6;    // 0..7
  const int wm = w >> 2;     // 0..1 : 128-row half
  const int wn = w & 3;      // 0..3 : 64-col quarter

  // XCD-aware bijective swizzle: 1536 = 8 XCDs x 192
  const int bid = blockIdx.x;
  const int swz = (bid & 7) * 192 + (bid >> 3);
  const int mat = swz >> 9;        // 0..2 (k,v,q)
  const int rem = swz & 511;
  const int tileM = rem >> 2;      // 0..127
  const int tileN = rem & 3;       // 0..3

  const _Float16* Ag = A + (size_t)tileM * 256 * DIMD;
  const _Float16* Bg = Wcat + (size_t)mat * NSTATE * DIMD + (size_t)tileN * 256 * DIMD;

  // staging: region = 256 rows x 32 k = 1024 slots x 8 f16; 2 slots/thread
  const int s0 = tid, s1 = tid + 512;
  const int sr0 = s0 >> 2, sc0 = ((s0 & 3) ^ ((s0 >> 3) & 3)) * 8;
  const int sr1 = s1 >> 2, sc1 = ((s1 & 3) ^ ((s1 >> 3) & 3)) * 8;

  // whole 32k region stage: 2 x global_load_lds(16B) per thread
#define STAGE_R(G, buf, reg, TT)                                                        \
  do {                                                                                  \
    __builtin_amdgcn_global_load_lds(                                                   \
        GAS(G + (size_t)sr0 * DIMD + (TT) * 32 + sc0),                                  \
        LAS(lds + (buf) * 16384 + (reg) * 8192 + s0 * 8), 16, 0, 0);                    \
    __builtin_amdgcn_global_load_lds(                                                   \
        GAS(G + (size_t)sr1 * DIMD + (TT) * 32 + sc1),                                  \
        LAS(lds + (buf) * 16384 + (reg) * 8192 + s1 * 8), 16, 0, 0);                    \
  } while (0)

  f32x4 acc[8][4];
#pragma unroll
  for (int m = 0; m < 8; ++m)
#pragma unroll
    for (int n = 0; n < 4; ++n)
      acc[m][n] = (f32x4){0.f, 0.f, 0.f, 0.f};

  // prologue: K-tile 0 (A then B)
  STAGE_R(Ag, 0, 0, 0);
  STAGE_R(Bg, 0, 1, 0);

  const int fr = lane & 15;
  const int cbp = ((lane >> 4) ^ ((fr >> 1) & 3)) * 8;   // phys cb elem offset

#define KTILE(T)                                                                        \
  do {                                                                                  \
    const int buf = (T) & 1, bufn = buf ^ 1;                                            \
    f16x8 a0[8], b0[4];                                                                 \
    /* -- PH0: drain A(T),B(T); barrier; stage A(T+1); 12 reads; MFMA n01 -- */         \
    asm volatile("s_waitcnt vmcnt(0)" ::: "memory");                                    \
    __builtin_amdgcn_s_barrier();                                                       \
    __builtin_amdgcn_sched_barrier(0);                                                  \
    if ((T) + 1 < 32) STAGE_R(Ag, bufn, 0, (T) + 1);                                    \
    _Pragma("unroll") for (int m = 0; m < 8; ++m)                                       \
        a0[m] = *(const f16x8*)(lds + buf * 16384 + 0 * 8192 +                          \
                                (wm * 128 + m * 16 + fr) * 32 + cbp);                   \
    _Pragma("unroll") for (int n = 0; n < 4; ++n)                                       \
        b0[n] = *(const f16x8*)(lds + buf * 16384 + 1 * 8192 +                          \
                                (wn * 64 + n * 16 + fr) * 32 + cbp);                    \
    __builtin_amdgcn_s_setprio(1);                                                      \
    _Pragma("unroll") for (int m = 0; m < 8; ++m) _Pragma("unroll") for (int n = 0; n < 2; ++n) \
        acc[m][n] = __builtin_amdgcn_mfma_f32_16x16x32_f16(a0[m], b0[n], acc[m][n], 0, 0, 0); \
    __builtin_amdgcn_s_setprio(0);                                                      \
    /* -- PH1: stage B(T+1); MFMA n23 -- */                                             \
    if ((T) + 1 < 32) STAGE_R(Bg, bufn, 1, (T) + 1);                                    \
    __builtin_amdgcn_s_setprio(1);                                                      \
    _Pragma("unroll") for (int m = 0; m < 8; ++m) _Pragma("unroll") for (int n = 2; n < 4; ++n) \
        acc[m][n] = __builtin_amdgcn_mfma_f32_16x16x32_f16(a0[m], b0[n], acc[m][n], 0, 0, 0); \
    __builtin_amdgcn_s_setprio(0);                                                      \
  } while (0)

  KTILE(0);  KTILE(1);  KTILE(2);  KTILE(3);
  KTILE(4);  KTILE(5);  KTILE(6);  KTILE(7);
  KTILE(8);  KTILE(9);  KTILE(10); KTILE(11);
  KTILE(12); KTILE(13); KTILE(14); KTILE(15);
  KTILE(16); KTILE(17); KTILE(18); KTILE(19);
  KTILE(20); KTILE(21); KTILE(22); KTILE(23);
  KTILE(24); KTILE(25); KTILE(26); KTILE(27);
  KTILE(28); KTILE(29); KTILE(30); KTILE(31);

  // ---- epilogue: blocked-transposed store [tchunk][c][8] ----
  const int cc = lane & 15;
  const int l4 = lane >> 4;
  _Float16* Cb = KVQt + (size_t)mat * ((size_t)MROWS * NSTATE) +
                 (size_t)(tileM * 2 + wm) * ((size_t)NCH * 8);
#pragma unroll
  for (int n = 0; n < 4; ++n)
#pragma unroll
    for (int j = 0; j < 4; ++j) {
      f16x8 pk;
#pragma unroll
      for (int m = 0; m < 8; ++m) pk[m] = (_Float16)acc[m][n][j];
      const int b = l4 * 4 + j;
      const int gcol = tileN * 256 + wn * 64 + n * 16 + cc;
      *(f16x8*)(Cb + ((size_t)(b * 1024 + gcol)) * 8) = pk;
    }

  // ---- k^2 row partials (mat 0), slot = tileN*4 + wn (deterministic) ----
  if (mat == 0) {
#pragma unroll
    for (int m = 0; m < 8; ++m)
#pragma unroll
      for (int j = 0; j < 4; ++j) {
        float p = 0.f;
#pragma unroll
        for (int n = 0; n < 4; ++n) p += acc[m][n][j] * acc[m][n][j];
        p += __shfl_xor(p, 1);
        p += __shfl_xor(p, 2);
        p += __shfl_xor(p, 4);
        p += __shfl_xor(p, 8);
        if (cc == 0) {
          const int gr = tileM * 256 + wm * 128 + m * 16 + l4 * 4 + j;
          rnpart[(size_t)(tileN * 4 + wn) * MROWS + gr] = p;
        }
      }
  }
}

// ---------------- finalize: rnT[b][t] = 1/(||k_row|| + eps), transposed ----------------
__global__ void rnfin_kernel(const float* __restrict__ part, float* __restrict__ rnT) {
  const int r = blockIdx.x * 256 + threadIdx.x;
  float s = 0.f;
#pragma unroll
  for (int i = 0; i < 16; ++i) s += part[(size_t)i * MROWS + r];
  rnT[(r & 15) * T_STEPS + (r >> 4)] = 1.f / (sqrtf(s) + 1e-6f);
}

// ---------------- scan: 2-wave producer/consumer, Padé-5/4 tanh chain ----------
// (unchanged from round 16)
#define STILE 16

#define LOADKV(P, t0in)                                                       \
  do {                                                                        \
    const int tc = ((t0in) < T_STEPS) ? (t0in) : (T_STEPS - STILE);           \
    const size_t o0 = ((size_t)(tc >> 3) * NCH + c) * 8;                      \
    P##k0 = *(const f16x8*)(Kt + o0);                                         \
    P##k1 = *(const f16x8*)(Kt + o0 + (size_t)NCH * 8);                       \
    P##v0 = *(const f16x8*)(Vt + o0);                                         \
    P##v1 = *(const f16x8*)(Vt + o0 + (size_t)NCH * 8);                       \
    P##r0 = *(const f32x4*)(rnT + bb + tc);                                   \
    P##r1 = *(const f32x4*)(rnT + bb + tc + 4);                               \
    P##r2 = *(const f32x4*)(rnT + bb + tc + 8);                               \
    P##r3 = *(const f32x4*)(rnT + bb + tc + 12);                              \
  } while (0)

#define LOADQ(QP, t0in)                                                       \
  do {                                                                        \
    const int tc = ((t0in) < T_STEPS) ? (t0in) : (T_STEPS - STILE);           \
    const size_t o0 = ((size_t)(tc >> 3) * NCH + c) * 8;                      \
    QP##0 = *(const f16x8*)(Qt + o0);                                         \
    QP##1 = *(const f16x8*)(Qt + o0 + (size_t)NCH * 8);                       \
  } while (0)

// recurrence over one 16-step tile (Padé tanh); stores S per step into SvL[p]
#define CHAINL(P, p)                                                          \
  do {                                                                        \
    float pA[STILE], pB[STILE];                                               \
    _Pragma("unroll") for (int i = 0; i < STILE; ++i) {                       \
      float kf = (float)((i < 8) ? P##k0[i & 7] : P##k1[i & 7]);              \
      float vf = (float)((i < 8) ? P##v0[i & 7] : P##v1[i & 7]);              \
      float rv = (i < 4) ? P##r0[i & 3]                                       \
               : (i < 8) ? P##r1[i & 3]                                       \
               : (i < 12) ? P##r2[i & 3] : P##r3[i & 3];                      \
      float kn = kf * rv;                                                     \
      pA[i] = fmaf(-kn, kn, 1.f);                                             \
      pB[i] = kn * vf;                                                        \
    }                                                                         \
    _Pragma("unroll") for (int i = 0; i < STILE; ++i) {                       \
      float x = fmaf(S, pA[i], pB[i]);                                        \
      float x2 = x * x;                                                       \
      float d = fmaf(x2, fmaf(x2, 15.f, 420.f), 945.f);                       \
      float n = fmaf(x2, fmaf(x2, 1.f, 105.f), 945.f);                        \
      float rd = __builtin_amdgcn_rcpf(d);                                    \
      float t = x * n;                                                        \
      S = t * rd;                                                             \
      SvL[p][i][lane] = S;                                                    \
    }                                                                         \
  } while (0)

// output pass for one tile from SvL[p]
#define OUTL(QP, t0, p)                                                       \
  do {                                                                        \
    _Pragma("unroll") for (int i = 0; i < STILE; ++i) {                       \
      float sv = SvL[p][i][lane];                                             \
      float qf = (float)((i < 8) ? QP##0[i & 7] : QP##1[i & 7]);              \
      float z = sv * qf;                                                      \
      float e = __builtin_amdgcn_exp2f(-L2E * z);                             \
      float sg = __builtin_amdgcn_rcpf(1.f + e);                              \
      out[(size_t)((t0) + i) * NCH + c] = (z * z) * sg;                       \
    }                                                                         \
  } while (0)

__global__ __launch_bounds__(128) void scan_kernel(const _Float16* __restrict__ Kt,
                                                   const _Float16* __restrict__ Vt,
                                                   const _Float16* __restrict__ Qt,
                                                   const float* __restrict__ rnT,
                                                   float* __restrict__ out,
                                                   float* __restrict__ sfin) {
  __shared__ float SvL[2][STILE][64];
  const int lane = threadIdx.x & 63;
  const bool isChain = threadIdx.x < 64;   // wave-uniform branch
  const int c = blockIdx.x * 64 + lane;    // 0..16383
  const int bb = (c >> 10) * T_STEPS;
  constexpr float L2E = 1.4426950408889634f;     // log2(e)
  float S = 0.f;                                 // chain state
  f16x8 Ak0, Ak1, Av0, Av1, Bk0, Bk1, Bv0, Bv1;
  f32x4 Ar0, Ar1, Ar2, Ar3, Br0, Br1, Br2, Br3;
  f16x8 Qe0, Qe1, Qo0, Qo1;

  if (isChain) {
    LOADKV(A, 0);
    LOADKV(B, STILE);
  } else {
    LOADQ(Qe, 0);
  }

  for (int j = 0; j < T_STEPS / 32; ++j) {   // 64 iters, tiles 2j and 2j+1
    const int t0 = j * 32;
    // phase a: chain tile 2j -> Sv0 ; out tile 2j-1 from Sv1
    if (isChain) {
      CHAINL(A, 0);
      LOADKV(A, t0 + 2 * STILE);   // clamped at tail
    } else {
      if (j > 0) OUTL(Qo, t0 - STILE, 1);
      LOADQ(Qo, t0 + STILE);       // clamped
    }
    __syncthreads();
    // phase b: chain tile 2j+1 -> Sv1 ; out tile 2j from Sv0
    if (isChain) {
      CHAINL(B, 1);
      LOADKV(B, t0 + 3 * STILE);   // clamped
    } else {
      OUTL(Qe, t0, 0);
      LOADQ(Qe, t0 + 2 * STILE);   // clamped
    }
    __syncthreads();
  }
  if (isChain) {
    sfin[c] = S;
  } else {
    OUTL(Qo, T_STEPS - STILE, 1);  // tile 127, written in last phase b
  }
}

extern "C" void kernel_launch(void* const* d_in, const int* in_sizes, int n_in,
                              void* d_out, int out_size, void* d_ws, size_t ws_size,
                              hipStream_t stream) {
  const float* x = (const float*)d_in[0];
  const float* Wk = (const float*)d_in[1];
  const float* Wv = (const float*)d_in[2];
  const float* Wq = (const float*)d_in[3];

  char* ws = (char*)d_ws;
  _Float16* xh = (_Float16*)ws;                                   // 64 MiB
  _Float16* Wh = (_Float16*)(ws + 67108864ull);                   // 6 MiB
  _Float16* KVQt = (_Float16*)(ws + 67108864ull + 6291456ull);    // 192 MiB
  float* rnpart = (float*)(ws + 67108864ull + 6291456ull + 201326592ull);           // 2 MiB
  float* rnT = (float*)(ws + 67108864ull + 6291456ull + 201326592ull + 2097152ull); // 128 KiB

  int n8x = MROWS * DIMD / 8;
  cvt_kernel<<<(n8x + 255) / 256, 256, 0, stream>>>(x, xh, n8x);
  cvtW_kernel<<<dim3(NSTATE * DIMD / 8 / 256, 3), 256, 0, stream>>>(Wk, Wv, Wq, Wh);

  gemm_kernel<<<1536, 512, 0, stream>>>(xh, Wh, KVQt, rnpart);

  rnfin_kernel<<<MROWS / 256, 256, 0, stream>>>(rnpart, rnT);

  const _Float16* Kt = KVQt;
  const _Float16* Vt = KVQt + (size_t)MROWS * NSTATE;
  const _Float16* Qt = KVQt + 2ull * MROWS * NSTATE;
  float* outp = (float*)d_out;
  scan_kernel<<<NCH / 64, 128, 0, stream>>>(Kt, Vt, Qt, rnT, outp, outp + (size_t)MROWS * NSTATE);
}

// Round 18
// 383.605 us; speedup vs baseline: 6.4892x; 6.4892x over previous
//
#include <hip/hip_runtime.h>
#include <hip/hip_fp16.h>

#define T_STEPS 2048
#define BATCH 16
#define DIMD 1024
#define NSTATE 1024
#define MROWS (T_STEPS * BATCH)   // 32768
#define NCH (BATCH * NSTATE)      // 16384

typedef _Float16 f16x8 __attribute__((ext_vector_type(8)));
typedef float f32x4 __attribute__((ext_vector_type(4)));

#define GAS(p) ((const __attribute__((address_space(1))) void*)(p))
#define LAS(p) ((__attribute__((address_space(3))) void*)(p))

// ---------------- f32 -> f16 convert, 8 elements/thread ----------------
__global__ void cvt_kernel(const float* __restrict__ src, _Float16* __restrict__ dst, int n8) {
  int i = blockIdx.x * blockDim.x + threadIdx.x;
  if (i >= n8) return;
  const float4* s4 = (const float4*)src;
  float4 a = s4[(size_t)i * 2];
  float4 b = s4[(size_t)i * 2 + 1];
  f16x8 o;
  o[0] = (_Float16)a.x; o[1] = (_Float16)a.y; o[2] = (_Float16)a.z; o[3] = (_Float16)a.w;
  o[4] = (_Float16)b.x; o[5] = (_Float16)b.y; o[6] = (_Float16)b.z; o[7] = (_Float16)b.w;
  *((f16x8*)dst + i) = o;
}

// one launch for all three W matrices (blockIdx.y selects)
__global__ void cvtW_kernel(const float* __restrict__ wk, const float* __restrict__ wv,
                            const float* __restrict__ wq, _Float16* __restrict__ dst) {
  const float* src = blockIdx.y == 0 ? wk : blockIdx.y == 1 ? wv : wq;
  int i = blockIdx.x * blockDim.x + threadIdx.x;   // < 131072
  const float4* s4 = (const float4*)src;
  float4 a = s4[(size_t)i * 2];
  float4 b = s4[(size_t)i * 2 + 1];
  f16x8 o;
  o[0] = (_Float16)a.x; o[1] = (_Float16)a.y; o[2] = (_Float16)a.z; o[3] = (_Float16)a.w;
  o[4] = (_Float16)b.x; o[5] = (_Float16)b.y; o[6] = (_Float16)b.z; o[7] = (_Float16)b.w;
  *((f16x8*)dst + (size_t)blockIdx.y * (NSTATE * DIMD / 8) + i) = o;
}

// ================= GEMM: 256x256 tile, BK=32, 8 waves, 2-phase, 2 blocks/CU ====
// Champion (2,4) wave decomp + phase bodies; BK 64->32 so LDS = 64 KiB and TWO
// blocks co-reside per CU (m97/m114 cross-block overlap absorbs the vmcnt(0)+
// barrier drain). __launch_bounds__(512,1): do NOT clamp the register allocator
// (round-17's (512,4) forced VGPR<=128 -> acc spilled -> 11 GB scratch traffic).
// Occupancy comes from the natural LDS/VGPR fit (120 VGPR <= 128 -> 16 waves/CU).
__global__ __launch_bounds__(512, 1) void gemm_kernel(const _Float16* __restrict__ A,
                                                      const _Float16* __restrict__ Wcat,
                                                      _Float16* __restrict__ KVQt,
                                                      float* __restrict__ rnpart) {
  __shared__ _Float16 lds[32768];   // [buf:2][region:2 (A,B)][8192]  = 64 KiB
  const int tid = threadIdx.x;
  const int lane = tid & 63;
  const int w = tid >> 6;    // 0..7
  const int wm = w >> 2;     // 0..1 : 128-row half
  const int wn = w & 3;      // 0..3 : 64-col quarter

  // XCD-aware bijective swizzle: 1536 = 8 XCDs x 192
  const int bid = blockIdx.x;
  const int swz = (bid & 7) * 192 + (bid >> 3);
  const int mat = swz >> 9;        // 0..2 (k,v,q)
  const int rem = swz & 511;
  const int tileM = rem >> 2;      // 0..127
  const int tileN = rem & 3;       // 0..3

  const _Float16* Ag = A + (size_t)tileM * 256 * DIMD;
  const _Float16* Bg = Wcat + (size_t)mat * NSTATE * DIMD + (size_t)tileN * 256 * DIMD;

  // staging: region = 256 rows x 32 k = 1024 slots x 8 f16; 2 slots/thread
  const int s0 = tid, s1 = tid + 512;
  const int sr0 = s0 >> 2, sc0 = ((s0 & 3) ^ ((s0 >> 3) & 3)) * 8;
  const int sr1 = s1 >> 2, sc1 = ((s1 & 3) ^ ((s1 >> 3) & 3)) * 8;

  // whole 32k region stage: 2 x global_load_lds(16B) per thread
#define STAGE_R(G, buf, reg, TT)                                                        \
  do {                                                                                  \
    __builtin_amdgcn_global_load_lds(                                                   \
        GAS(G + (size_t)sr0 * DIMD + (TT) * 32 + sc0),                                  \
        LAS(lds + (buf) * 16384 + (reg) * 8192 + s0 * 8), 16, 0, 0);                    \
    __builtin_amdgcn_global_load_lds(                                                   \
        GAS(G + (size_t)sr1 * DIMD + (TT) * 32 + sc1),                                  \
        LAS(lds + (buf) * 16384 + (reg) * 8192 + s1 * 8), 16, 0, 0);                    \
  } while (0)

  f32x4 acc[8][4];
#pragma unroll
  for (int m = 0; m < 8; ++m)
#pragma unroll
    for (int n = 0; n < 4; ++n)
      acc[m][n] = (f32x4){0.f, 0.f, 0.f, 0.f};

  // prologue: K-tile 0 (A then B)
  STAGE_R(Ag, 0, 0, 0);
  STAGE_R(Bg, 0, 1, 0);

  const int fr = lane & 15;
  const int cbp = ((lane >> 4) ^ ((fr >> 1) & 3)) * 8;   // phys cb elem offset

#define KTILE(T)                                                                        \
  do {                                                                                  \
    const int buf = (T) & 1, bufn = buf ^ 1;                                            \
    f16x8 a0[8], b0[4];                                                                 \
    /* -- PH0: drain A(T),B(T); barrier; stage A(T+1); 12 reads; MFMA n01 -- */         \
    asm volatile("s_waitcnt vmcnt(0)" ::: "memory");                                    \
    __builtin_amdgcn_s_barrier();                                                       \
    __builtin_amdgcn_sched_barrier(0);                                                  \
    if ((T) + 1 < 32) STAGE_R(Ag, bufn, 0, (T) + 1);                                    \
    _Pragma("unroll") for (int m = 0; m < 8; ++m)                                       \
        a0[m] = *(const f16x8*)(lds + buf * 16384 + 0 * 8192 +                          \
                                (wm * 128 + m * 16 + fr) * 32 + cbp);                   \
    _Pragma("unroll") for (int n = 0; n < 4; ++n)                                       \
        b0[n] = *(const f16x8*)(lds + buf * 16384 + 1 * 8192 +                          \
                                (wn * 64 + n * 16 + fr) * 32 + cbp);                    \
    __builtin_amdgcn_s_setprio(1);                                                      \
    _Pragma("unroll") for (int m = 0; m < 8; ++m) _Pragma("unroll") for (int n = 0; n < 2; ++n) \
        acc[m][n] = __builtin_amdgcn_mfma_f32_16x16x32_f16(a0[m], b0[n], acc[m][n], 0, 0, 0); \
    __builtin_amdgcn_s_setprio(0);                                                      \
    /* -- PH1: stage B(T+1); MFMA n23 -- */                                             \
    if ((T) + 1 < 32) STAGE_R(Bg, bufn, 1, (T) + 1);                                    \
    __builtin_amdgcn_s_setprio(1);                                                      \
    _Pragma("unroll") for (int m = 0; m < 8; ++m) _Pragma("unroll") for (int n = 2; n < 4; ++n) \
        acc[m][n] = __builtin_amdgcn_mfma_f32_16x16x32_f16(a0[m], b0[n], acc[m][n], 0, 0, 0); \
    __builtin_amdgcn_s_setprio(0);                                                      \
  } while (0)

  KTILE(0);  KTILE(1);  KTILE(2);  KTILE(3);
  KTILE(4);  KTILE(5);  KTILE(6);  KTILE(7);
  KTILE(8);  KTILE(9);  KTILE(10); KTILE(11);
  KTILE(12); KTILE(13); KTILE(14); KTILE(15);
  KTILE(16); KTILE(17); KTILE(18); KTILE(19);
  KTILE(20); KTILE(21); KTILE(22); KTILE(23);
  KTILE(24); KTILE(25); KTILE(26); KTILE(27);
  KTILE(28); KTILE(29); KTILE(30); KTILE(31);

  // ---- epilogue: blocked-transposed store [tchunk][c][8] ----
  const int cc = lane & 15;
  const int l4 = lane >> 4;
  _Float16* Cb = KVQt + (size_t)mat * ((size_t)MROWS * NSTATE) +
                 (size_t)(tileM * 2 + wm) * ((size_t)NCH * 8);
#pragma unroll
  for (int n = 0; n < 4; ++n)
#pragma unroll
    for (int j = 0; j < 4; ++j) {
      f16x8 pk;
#pragma unroll
      for (int m = 0; m < 8; ++m) pk[m] = (_Float16)acc[m][n][j];
      const int b = l4 * 4 + j;
      const int gcol = tileN * 256 + wn * 64 + n * 16 + cc;
      *(f16x8*)(Cb + ((size_t)(b * 1024 + gcol)) * 8) = pk;
    }

  // ---- k^2 row partials (mat 0), slot = tileN*4 + wn (deterministic) ----
  if (mat == 0) {
#pragma unroll
    for (int m = 0; m < 8; ++m)
#pragma unroll
      for (int j = 0; j < 4; ++j) {
        float p = 0.f;
#pragma unroll
        for (int n = 0; n < 4; ++n) p += acc[m][n][j] * acc[m][n][j];
        p += __shfl_xor(p, 1);
        p += __shfl_xor(p, 2);
        p += __shfl_xor(p, 4);
        p += __shfl_xor(p, 8);
        if (cc == 0) {
          const int gr = tileM * 256 + wm * 128 + m * 16 + l4 * 4 + j;
          rnpart[(size_t)(tileN * 4 + wn) * MROWS + gr] = p;
        }
      }
  }
}

// ---------------- finalize: rnT[b][t] = 1/(||k_row|| + eps), transposed ----------------
__global__ void rnfin_kernel(const float* __restrict__ part, float* __restrict__ rnT) {
  const int r = blockIdx.x * 256 + threadIdx.x;
  float s = 0.f;
#pragma unroll
  for (int i = 0; i < 16; ++i) s += part[(size_t)i * MROWS + r];
  rnT[(r & 15) * T_STEPS + (r >> 4)] = 1.f / (sqrtf(s) + 1e-6f);
}

// ---------------- scan: 2-wave producer/consumer, Padé-5/4 tanh chain ----------
// (unchanged champion from round 16)
#define STILE 16

#define LOADKV(P, t0in)                                                       \
  do {                                                                        \
    const int tc = ((t0in) < T_STEPS) ? (t0in) : (T_STEPS - STILE);           \
    const size_t o0 = ((size_t)(tc >> 3) * NCH + c) * 8;                      \
    P##k0 = *(const f16x8*)(Kt + o0);                                         \
    P##k1 = *(const f16x8*)(Kt + o0 + (size_t)NCH * 8);                       \
    P##v0 = *(const f16x8*)(Vt + o0);                                         \
    P##v1 = *(const f16x8*)(Vt + o0 + (size_t)NCH * 8);                       \
    P##r0 = *(const f32x4*)(rnT + bb + tc);                                   \
    P##r1 = *(const f32x4*)(rnT + bb + tc + 4);                               \
    P##r2 = *(const f32x4*)(rnT + bb + tc + 8);                               \
    P##r3 = *(const f32x4*)(rnT + bb + tc + 12);                              \
  } while (0)

#define LOADQ(QP, t0in)                                                       \
  do {                                                                        \
    const int tc = ((t0in) < T_STEPS) ? (t0in) : (T_STEPS - STILE);           \
    const size_t o0 = ((size_t)(tc >> 3) * NCH + c) * 8;                      \
    QP##0 = *(const f16x8*)(Qt + o0);                                         \
    QP##1 = *(const f16x8*)(Qt + o0 + (size_t)NCH * 8);                       \
  } while (0)

// recurrence over one 16-step tile (Padé tanh); stores S per step into SvL[p]
#define CHAINL(P, p)                                                          \
  do {                                                                        \
    float pA[STILE], pB[STILE];                                               \
    _Pragma("unroll") for (int i = 0; i < STILE; ++i) {                       \
      float kf = (float)((i < 8) ? P##k0[i & 7] : P##k1[i & 7]);              \
      float vf = (float)((i < 8) ? P##v0[i & 7] : P##v1[i & 7]);              \
      float rv = (i < 4) ? P##r0[i & 3]                                       \
               : (i < 8) ? P##r1[i & 3]                                       \
               : (i < 12) ? P##r2[i & 3] : P##r3[i & 3];                      \
      float kn = kf * rv;                                                     \
      pA[i] = fmaf(-kn, kn, 1.f);                                             \
      pB[i] = kn * vf;                                                        \
    }                                                                         \
    _Pragma("unroll") for (int i = 0; i < STILE; ++i) {                       \
      float x = fmaf(S, pA[i], pB[i]);                                        \
      float x2 = x * x;                                                       \
      float d = fmaf(x2, fmaf(x2, 15.f, 420.f), 945.f);                       \
      float n = fmaf(x2, fmaf(x2, 1.f, 105.f), 945.f);                        \
      float rd = __builtin_amdgcn_rcpf(d);                                    \
      float t = x * n;                                                        \
      S = t * rd;                                                             \
      SvL[p][i][lane] = S;                                                    \
    }                                                                         \
  } while (0)

// output pass for one tile from SvL[p]
#define OUTL(QP, t0, p)                                                       \
  do {                                                                        \
    _Pragma("unroll") for (int i = 0; i < STILE; ++i) {                       \
      float sv = SvL[p][i][lane];                                             \
      float qf = (float)((i < 8) ? QP##0[i & 7] : QP##1[i & 7]);              \
      float z = sv * qf;                                                      \
      float e = __builtin_amdgcn_exp2f(-L2E * z);                             \
      float sg = __builtin_amdgcn_rcpf(1.f + e);                              \
      out[(size_t)((t0) + i) * NCH + c] = (z * z) * sg;                       \
    }                                                                         \
  } while (0)

__global__ __launch_bounds__(128) void scan_kernel(const _Float16* __restrict__ Kt,
                                                   const _Float16* __restrict__ Vt,
                                                   const _Float16* __restrict__ Qt,
                                                   const float* __restrict__ rnT,
                                                   float* __restrict__ out,
                                                   float* __restrict__ sfin) {
  __shared__ float SvL[2][STILE][64];
  const int lane = threadIdx.x & 63;
  const bool isChain = threadIdx.x < 64;   // wave-uniform branch
  const int c = blockIdx.x * 64 + lane;    // 0..16383
  const int bb = (c >> 10) * T_STEPS;
  constexpr float L2E = 1.4426950408889634f;     // log2(e)
  float S = 0.f;                                 // chain state
  f16x8 Ak0, Ak1, Av0, Av1, Bk0, Bk1, Bv0, Bv1;
  f32x4 Ar0, Ar1, Ar2, Ar3, Br0, Br1, Br2, Br3;
  f16x8 Qe0, Qe1, Qo0, Qo1;

  if (isChain) {
    LOADKV(A, 0);
    LOADKV(B, STILE);
  } else {
    LOADQ(Qe, 0);
  }

  for (int j = 0; j < T_STEPS / 32; ++j) {   // 64 iters, tiles 2j and 2j+1
    const int t0 = j * 32;
    // phase a: chain tile 2j -> Sv0 ; out tile 2j-1 from Sv1
    if (isChain) {
      CHAINL(A, 0);
      LOADKV(A, t0 + 2 * STILE);   // clamped at tail
    } else {
      if (j > 0) OUTL(Qo, t0 - STILE, 1);
      LOADQ(Qo, t0 + STILE);       // clamped
    }
    __syncthreads();
    // phase b: chain tile 2j+1 -> Sv1 ; out tile 2j from Sv0
    if (isChain) {
      CHAINL(B, 1);
      LOADKV(B, t0 + 3 * STILE);   // clamped
    } else {
      OUTL(Qe, t0, 0);
      LOADQ(Qe, t0 + 2 * STILE);   // clamped
    }
    __syncthreads();
  }
  if (isChain) {
    sfin[c] = S;
  } else {
    OUTL(Qo, T_STEPS - STILE, 1);  // tile 127, written in last phase b
  }
}

extern "C" void kernel_launch(void* const* d_in, const int* in_sizes, int n_in,
                              void* d_out, int out_size, void* d_ws, size_t ws_size,
                              hipStream_t stream) {
  const float* x = (const float*)d_in[0];
  const float* Wk = (const float*)d_in[1];
  const float* Wv = (const float*)d_in[2];
  const float* Wq = (const float*)d_in[3];

  char* ws = (char*)d_ws;
  _Float16* xh = (_Float16*)ws;                                   // 64 MiB
  _Float16* Wh = (_Float16*)(ws + 67108864ull);                   // 6 MiB
  _Float16* KVQt = (_Float16*)(ws + 67108864ull + 6291456ull);    // 192 MiB
  float* rnpart = (float*)(ws + 67108864ull + 6291456ull + 201326592ull);           // 2 MiB
  float* rnT = (float*)(ws + 67108864ull + 6291456ull + 201326592ull + 2097152ull); // 128 KiB

  int n8x = MROWS * DIMD / 8;
  cvt_kernel<<<(n8x + 255) / 256, 256, 0, stream>>>(x, xh, n8x);
  cvtW_kernel<<<dim3(NSTATE * DIMD / 8 / 256, 3), 256, 0, stream>>>(Wk, Wv, Wq, Wh);

  gemm_kernel<<<1536, 512, 0, stream>>>(xh, Wh, KVQt, rnpart);

  rnfin_kernel<<<MROWS / 256, 256, 0, stream>>>(rnpart, rnT);

  const _Float16* Kt = KVQt;
  const _Float16* Vt = KVQt + (size_t)MROWS * NSTATE;
  const _Float16* Qt = KVQt + 2ull * MROWS * NSTATE;
  float* outp = (float*)d_out;
  scan_kernel<<<NCH / 64, 128, 0, stream>>>(Kt, Vt, Qt, rnT, outp, outp + (size_t)MROWS * NSTATE);
}

// Round 19
// 371.466 us; speedup vs baseline: 6.7012x; 1.0327x over previous
//
#include <hip/hip_runtime.h>
#include <hip/hip_fp16.h>

#define T_STEPS 2048
#define BATCH 16
#define DIMD 1024
#define NSTATE 1024
#define MROWS (T_STEPS * BATCH)   // 32768
#define NCH (BATCH * NSTATE)      // 16384

typedef _Float16 f16x8 __attribute__((ext_vector_type(8)));
typedef float f32x4 __attribute__((ext_vector_type(4)));

#define GAS(p) ((const __attribute__((address_space(1))) void*)(p))
#define LAS(p) ((__attribute__((address_space(3))) void*)(p))

// ---------------- f32 -> f16 convert, 8 elements/thread ----------------
__global__ void cvt_kernel(const float* __restrict__ src, _Float16* __restrict__ dst, int n8) {
  int i = blockIdx.x * blockDim.x + threadIdx.x;
  if (i >= n8) return;
  const float4* s4 = (const float4*)src;
  float4 a = s4[(size_t)i * 2];
  float4 b = s4[(size_t)i * 2 + 1];
  f16x8 o;
  o[0] = (_Float16)a.x; o[1] = (_Float16)a.y; o[2] = (_Float16)a.z; o[3] = (_Float16)a.w;
  o[4] = (_Float16)b.x; o[5] = (_Float16)b.y; o[6] = (_Float16)b.z; o[7] = (_Float16)b.w;
  *((f16x8*)dst + i) = o;
}

// one launch for all three W matrices (blockIdx.y selects)
__global__ void cvtW_kernel(const float* __restrict__ wk, const float* __restrict__ wv,
                            const float* __restrict__ wq, _Float16* __restrict__ dst) {
  const float* src = blockIdx.y == 0 ? wk : blockIdx.y == 1 ? wv : wq;
  int i = blockIdx.x * blockDim.x + threadIdx.x;   // < 131072
  const float4* s4 = (const float4*)src;
  float4 a = s4[(size_t)i * 2];
  float4 b = s4[(size_t)i * 2 + 1];
  f16x8 o;
  o[0] = (_Float16)a.x; o[1] = (_Float16)a.y; o[2] = (_Float16)a.z; o[3] = (_Float16)a.w;
  o[4] = (_Float16)b.x; o[5] = (_Float16)b.y; o[6] = (_Float16)b.z; o[7] = (_Float16)b.w;
  *((f16x8*)dst + (size_t)blockIdx.y * (NSTATE * DIMD / 8) + i) = o;
}

// ================= GEMM: 256x256 tile, BK=64, 8 waves, k-split 4-phase =========
// (measured-best variant: ~206 us / MfmaUtil 45.6% — restored champion)
__global__ __launch_bounds__(512, 1) void gemm_kernel(const _Float16* __restrict__ A,
                                                      const _Float16* __restrict__ Wcat,
                                                      _Float16* __restrict__ KVQt,
                                                      float* __restrict__ rnpart) {
  __shared__ _Float16 lds[65536];   // [buf:2][half:4 (Aklo,Akhi,Bklo,Bkhi)][8192]
  const int tid = threadIdx.x;
  const int lane = tid & 63;
  const int w = tid >> 6;    // 0..7
  const int wm = w >> 2;     // 0..1 : 128-row half
  const int wn = w & 3;      // 0..3 : 64-col quarter

  // XCD-aware bijective swizzle: 1536 = 8 XCDs x 192
  const int bid = blockIdx.x;
  const int swz = (bid & 7) * 192 + (bid >> 3);
  const int mat = swz >> 9;        // 0..2 (k,v,q)
  const int rem = swz & 511;
  const int tileM = rem >> 2;      // 0..127
  const int tileN = rem & 3;       // 0..3

  const _Float16* Ag = A + (size_t)tileM * 256 * DIMD;
  const _Float16* Bg = Wcat + (size_t)mat * NSTATE * DIMD + (size_t)tileN * 256 * DIMD;

  // staging: half-tile = 256 rows x 32 k = 1024 slots x 8 f16; 2 slots/thread
  const int s0 = tid, s1 = tid + 512;
  const int sr0 = s0 >> 2, sc0 = ((s0 & 3) ^ ((s0 >> 3) & 3)) * 8;
  const int sr1 = s1 >> 2, sc1 = ((s1 & 3) ^ ((s1 >> 3) & 3)) * 8;

#define STAGE_H(G, buf, reg, TT, h)                                                     \
  do {                                                                                  \
    __builtin_amdgcn_global_load_lds(                                                   \
        GAS(G + (size_t)sr0 * DIMD + (TT) * 64 + (h) * 32 + sc0),                       \
        LAS(lds + (buf) * 32768 + (reg) * 8192 + s0 * 8), 16, 0, 0);                    \
    __builtin_amdgcn_global_load_lds(                                                   \
        GAS(G + (size_t)sr1 * DIMD + (TT) * 64 + (h) * 32 + sc1),                       \
        LAS(lds + (buf) * 32768 + (reg) * 8192 + s1 * 8), 16, 0, 0);                    \
  } while (0)

  f32x4 acc[8][4];
#pragma unroll
  for (int m = 0; m < 8; ++m)
#pragma unroll
    for (int n = 0; n < 4; ++n)
      acc[m][n] = (f32x4){0.f, 0.f, 0.f, 0.f};

  // prologue: K-tile 0, FIFO order Aklo,Bklo,Akhi,Bkhi
  STAGE_H(Ag, 0, 0, 0, 0);
  STAGE_H(Bg, 0, 2, 0, 0);
  STAGE_H(Ag, 0, 1, 0, 1);
  STAGE_H(Bg, 0, 3, 0, 1);

  const int fr = lane & 15;
  const int cbp = ((lane >> 4) ^ ((fr >> 1) & 3)) * 8;   // phys cb elem offset

#define KTILE(T)                                                                        \
  do {                                                                                  \
    const int buf = (T) & 1, bufn = buf ^ 1;                                            \
    f16x8 a0[8], b0[4], a1[8], b1[4];                                                   \
    /* -- PH0: guard Aklo(T),Bklo(T); stage Aklo(T+1); MFMA ks0 x n01 -- */             \
    asm volatile("s_waitcnt vmcnt(4)" ::: "memory");                                    \
    __builtin_amdgcn_s_barrier();                                                       \
    __builtin_amdgcn_sched_barrier(0);                                                  \
    if ((T) + 1 < 16) STAGE_H(Ag, bufn, 0, (T) + 1, 0);                                 \
    _Pragma("unroll") for (int m = 0; m < 8; ++m)                                       \
        a0[m] = *(const f16x8*)(lds + buf * 32768 + 0 * 8192 +                          \
                                (wm * 128 + m * 16 + fr) * 32 + cbp);                   \
    _Pragma("unroll") for (int n = 0; n < 4; ++n)                                       \
        b0[n] = *(const f16x8*)(lds + buf * 32768 + 2 * 8192 +                          \
                                (wn * 64 + n * 16 + fr) * 32 + cbp);                    \
    __builtin_amdgcn_s_setprio(1);                                                      \
    _Pragma("unroll") for (int m = 0; m < 8; ++m) _Pragma("unroll") for (int n = 0; n < 2; ++n) \
        acc[m][n] = __builtin_amdgcn_mfma_f32_16x16x32_f16(a0[m], b0[n], acc[m][n], 0, 0, 0); \
    __builtin_amdgcn_s_setprio(0);                                                      \
    /* -- PH1: stage Blo(T+1); MFMA ks0 x n23 -- */                                     \
    if ((T) + 1 < 16) STAGE_H(Bg, bufn, 2, (T) + 1, 0);                                 \
    __builtin_amdgcn_s_setprio(1);                                                      \
    _Pragma("unroll") for (int m = 0; m < 8; ++m) _Pragma("unroll") for (int n = 2; n < 4; ++n) \
        acc[m][n] = __builtin_amdgcn_mfma_f32_16x16x32_f16(a0[m], b0[n], acc[m][n], 0, 0, 0); \
    __builtin_amdgcn_s_setprio(0);                                                      \
    /* -- PH2: guard Akhi(T),Bkhi(T); stage Ahi(T+1); MFMA ks1 x n01 -- */              \
    if ((T) + 1 < 16) {                                                                 \
      asm volatile("s_waitcnt vmcnt(4)" ::: "memory");                                  \
    } else {                                                                            \
      asm volatile("s_waitcnt vmcnt(0)" ::: "memory");                                  \
    }                                                                                   \
    __builtin_amdgcn_s_barrier();                                                       \
    __builtin_amdgcn_sched_barrier(0);                                                  \
    if ((T) + 1 < 16) STAGE_H(Ag, bufn, 1, (T) + 1, 1);                                 \
    _Pragma("unroll") for (int m = 0; m < 8; ++m)                                       \
        a1[m] = *(const f16x8*)(lds + buf * 32768 + 1 * 8192 +                          \
                                (wm * 128 + m * 16 + fr) * 32 + cbp);                   \
    _Pragma("unroll") for (int n = 0; n < 4; ++n)                                       \
        b1[n] = *(const f16x8*)(lds + buf * 32768 + 3 * 8192 +                          \
                                (wn * 64 + n * 16 + fr) * 32 + cbp);                    \
    __builtin_amdgcn_s_setprio(1);                                                      \
    _Pragma("unroll") for (int m = 0; m < 8; ++m) _Pragma("unroll") for (int n = 0; n < 2; ++n) \
        acc[m][n] = __builtin_amdgcn_mfma_f32_16x16x32_f16(a1[m], b1[n], acc[m][n], 0, 0, 0); \
    __builtin_amdgcn_s_setprio(0);                                                      \
    /* -- PH3: stage Bhi(T+1); MFMA ks1 x n23 -- */                                     \
    if ((T) + 1 < 16) STAGE_H(Bg, bufn, 3, (T) + 1, 1);                                 \
    __builtin_amdgcn_s_setprio(1);                                                      \
    _Pragma("unroll") for (int m = 0; m < 8; ++m) _Pragma("unroll") for (int n = 2; n < 4; ++n) \
        acc[m][n] = __builtin_amdgcn_mfma_f32_16x16x32_f16(a1[m], b1[n], acc[m][n], 0, 0, 0); \
    __builtin_amdgcn_s_setprio(0);                                                      \
  } while (0)

  KTILE(0);  KTILE(1);  KTILE(2);  KTILE(3);
  KTILE(4);  KTILE(5);  KTILE(6);  KTILE(7);
  KTILE(8);  KTILE(9);  KTILE(10); KTILE(11);
  KTILE(12); KTILE(13); KTILE(14); KTILE(15);

  // ---- epilogue: blocked-transposed store [tchunk][c][8] ----
  const int cc = lane & 15;
  const int l4 = lane >> 4;
  _Float16* Cb = KVQt + (size_t)mat * ((size_t)MROWS * NSTATE) +
                 (size_t)(tileM * 2 + wm) * ((size_t)NCH * 8);
#pragma unroll
  for (int n = 0; n < 4; ++n)
#pragma unroll
    for (int j = 0; j < 4; ++j) {
      f16x8 pk;
#pragma unroll
      for (int m = 0; m < 8; ++m) pk[m] = (_Float16)acc[m][n][j];
      const int b = l4 * 4 + j;
      const int gcol = tileN * 256 + wn * 64 + n * 16 + cc;
      *(f16x8*)(Cb + ((size_t)(b * 1024 + gcol)) * 8) = pk;
    }

  // ---- k^2 row partials (mat 0), slot = tileN*4 + wn (deterministic) ----
  if (mat == 0) {
#pragma unroll
    for (int m = 0; m < 8; ++m)
#pragma unroll
      for (int j = 0; j < 4; ++j) {
        float p = 0.f;
#pragma unroll
        for (int n = 0; n < 4; ++n) p += acc[m][n][j] * acc[m][n][j];
        p += __shfl_xor(p, 1);
        p += __shfl_xor(p, 2);
        p += __shfl_xor(p, 4);
        p += __shfl_xor(p, 8);
        if (cc == 0) {
          const int gr = tileM * 256 + wm * 128 + m * 16 + l4 * 4 + j;
          rnpart[(size_t)(tileN * 4 + wn) * MROWS + gr] = p;
        }
      }
  }
}

// ---------------- finalize: rnT[b][t] = 1/(||k_row|| + eps), transposed ----------------
__global__ void rnfin_kernel(const float* __restrict__ part, float* __restrict__ rnT) {
  const int r = blockIdx.x * 256 + threadIdx.x;
  float s = 0.f;
#pragma unroll
  for (int i = 0; i < 16; ++i) s += part[(size_t)i * MROWS + r];
  rnT[(r & 15) * T_STEPS + (r >> 4)] = 1.f / (sqrtf(s) + 1e-6f);
}

// ---------------- scan: 2-wave producer/consumer, Padé-5/4 tanh chain ----------
// (champion from round 16)
#define STILE 16

#define LOADKV(P, t0in)                                                       \
  do {                                                                        \
    const int tc = ((t0in) < T_STEPS) ? (t0in) : (T_STEPS - STILE);           \
    const size_t o0 = ((size_t)(tc >> 3) * NCH + c) * 8;                      \
    P##k0 = *(const f16x8*)(Kt + o0);                                         \
    P##k1 = *(const f16x8*)(Kt + o0 + (size_t)NCH * 8);                       \
    P##v0 = *(const f16x8*)(Vt + o0);                                         \
    P##v1 = *(const f16x8*)(Vt + o0 + (size_t)NCH * 8);                       \
    P##r0 = *(const f32x4*)(rnT + bb + tc);                                   \
    P##r1 = *(const f32x4*)(rnT + bb + tc + 4);                               \
    P##r2 = *(const f32x4*)(rnT + bb + tc + 8);                               \
    P##r3 = *(const f32x4*)(rnT + bb + tc + 12);                              \
  } while (0)

#define LOADQ(QP, t0in)                                                       \
  do {                                                                        \
    const int tc = ((t0in) < T_STEPS) ? (t0in) : (T_STEPS - STILE);           \
    const size_t o0 = ((size_t)(tc >> 3) * NCH + c) * 8;                      \
    QP##0 = *(const f16x8*)(Qt + o0);                                         \
    QP##1 = *(const f16x8*)(Qt + o0 + (size_t)NCH * 8);                       \
  } while (0)

// recurrence over one 16-step tile (Padé tanh); stores S per step into SvL[p]
#define CHAINL(P, p)                                                          \
  do {                                                                        \
    float pA[STILE], pB[STILE];                                               \
    _Pragma("unroll") for (int i = 0; i < STILE; ++i) {                       \
      float kf = (float)((i < 8) ? P##k0[i & 7] : P##k1[i & 7]);              \
      float vf = (float)((i < 8) ? P##v0[i & 7] : P##v1[i & 7]);              \
      float rv = (i < 4) ? P##r0[i & 3]                                       \
               : (i < 8) ? P##r1[i & 3]                                       \
               : (i < 12) ? P##r2[i & 3] : P##r3[i & 3];                      \
      float kn = kf * rv;                                                     \
      pA[i] = fmaf(-kn, kn, 1.f);                                             \
      pB[i] = kn * vf;                                                        \
    }                                                                         \
    _Pragma("unroll") for (int i = 0; i < STILE; ++i) {                       \
      float x = fmaf(S, pA[i], pB[i]);                                        \
      float x2 = x * x;                                                       \
      float d = fmaf(x2, fmaf(x2, 15.f, 420.f), 945.f);                       \
      float n = fmaf(x2, fmaf(x2, 1.f, 105.f), 945.f);                        \
      float rd = __builtin_amdgcn_rcpf(d);                                    \
      float t = x * n;                                                        \
      S = t * rd;                                                             \
      SvL[p][i][lane] = S;                                                    \
    }                                                                         \
  } while (0)

// output pass for one tile from SvL[p]
#define OUTL(QP, t0, p)                                                       \
  do {                                                                        \
    _Pragma("unroll") for (int i = 0; i < STILE; ++i) {                       \
      float sv = SvL[p][i][lane];                                             \
      float qf = (float)((i < 8) ? QP##0[i & 7] : QP##1[i & 7]);              \
      float z = sv * qf;                                                      \
      float e = __builtin_amdgcn_exp2f(-L2E * z);                             \
      float sg = __builtin_amdgcn_rcpf(1.f + e);                              \
      out[(size_t)((t0) + i) * NCH + c] = (z * z) * sg;                       \
    }                                                                         \
  } while (0)

__global__ __launch_bounds__(128) void scan_kernel(const _Float16* __restrict__ Kt,
                                                   const _Float16* __restrict__ Vt,
                                                   const _Float16* __restrict__ Qt,
                                                   const float* __restrict__ rnT,
                                                   float* __restrict__ out,
                                                   float* __restrict__ sfin) {
  __shared__ float SvL[2][STILE][64];
  const int lane = threadIdx.x & 63;
  const bool isChain = threadIdx.x < 64;   // wave-uniform branch
  const int c = blockIdx.x * 64 + lane;    // 0..16383
  const int bb = (c >> 10) * T_STEPS;
  constexpr float L2E = 1.4426950408889634f;     // log2(e)
  float S = 0.f;                                 // chain state
  f16x8 Ak0, Ak1, Av0, Av1, Bk0, Bk1, Bv0, Bv1;
  f32x4 Ar0, Ar1, Ar2, Ar3, Br0, Br1, Br2, Br3;
  f16x8 Qe0, Qe1, Qo0, Qo1;

  if (isChain) {
    LOADKV(A, 0);
    LOADKV(B, STILE);
  } else {
    LOADQ(Qe, 0);
  }

  for (int j = 0; j < T_STEPS / 32; ++j) {   // 64 iters, tiles 2j and 2j+1
    const int t0 = j * 32;
    // phase a: chain tile 2j -> Sv0 ; out tile 2j-1 from Sv1
    if (isChain) {
      CHAINL(A, 0);
      LOADKV(A, t0 + 2 * STILE);   // clamped at tail
    } else {
      if (j > 0) OUTL(Qo, t0 - STILE, 1);
      LOADQ(Qo, t0 + STILE);       // clamped
    }
    __syncthreads();
    // phase b: chain tile 2j+1 -> Sv1 ; out tile 2j from Sv0
    if (isChain) {
      CHAINL(B, 1);
      LOADKV(B, t0 + 3 * STILE);   // clamped
    } else {
      OUTL(Qe, t0, 0);
      LOADQ(Qe, t0 + 2 * STILE);   // clamped
    }
    __syncthreads();
  }
  if (isChain) {
    sfin[c] = S;
  } else {
    OUTL(Qo, T_STEPS - STILE, 1);  // tile 127, written in last phase b
  }
}

extern "C" void kernel_launch(void* const* d_in, const int* in_sizes, int n_in,
                              void* d_out, int out_size, void* d_ws, size_t ws_size,
                              hipStream_t stream) {
  const float* x = (const float*)d_in[0];
  const float* Wk = (const float*)d_in[1];
  const float* Wv = (const float*)d_in[2];
  const float* Wq = (const float*)d_in[3];

  char* ws = (char*)d_ws;
  _Float16* xh = (_Float16*)ws;                                   // 64 MiB
  _Float16* Wh = (_Float16*)(ws + 67108864ull);                   // 6 MiB
  _Float16* KVQt = (_Float16*)(ws + 67108864ull + 6291456ull);    // 192 MiB
  float* rnpart = (float*)(ws + 67108864ull + 6291456ull + 201326592ull);           // 2 MiB
  float* rnT = (float*)(ws + 67108864ull + 6291456ull + 201326592ull + 2097152ull); // 128 KiB

  int n8x = MROWS * DIMD / 8;
  cvt_kernel<<<(n8x + 255) / 256, 256, 0, stream>>>(x, xh, n8x);
  cvtW_kernel<<<dim3(NSTATE * DIMD / 8 / 256, 3), 256, 0, stream>>>(Wk, Wv, Wq, Wh);

  gemm_kernel<<<1536, 512, 0, stream>>>(xh, Wh, KVQt, rnpart);

  rnfin_kernel<<<MROWS / 256, 256, 0, stream>>>(rnpart, rnT);

  const _Float16* Kt = KVQt;
  const _Float16* Vt = KVQt + (size_t)MROWS * NSTATE;
  const _Float16* Qt = KVQt + 2ull * MROWS * NSTATE;
  float* outp = (float*)d_out;
  scan_kernel<<<NCH / 64, 128, 0, stream>>>(Kt, Vt, Qt, rnT, outp, outp + (size_t)MROWS * NSTATE);
}